// Round 13
// baseline (754.240 us; speedup 1.0000x reference)
//
#include <hip/hip_runtime.h>

typedef __bf16 bf16x8 __attribute__((ext_vector_type(8)));
typedef float f32x4 __attribute__((ext_vector_type(4)));
typedef unsigned short u16x8 __attribute__((ext_vector_type(8)));
typedef unsigned short u16x4 __attribute__((ext_vector_type(4)));

#define MFMA16(a, b, c) __builtin_amdgcn_mfma_f32_16x16x32_bf16((a), (b), (c), 0, 0, 0)
#define GLOAD_LDS(gp, lp) __builtin_amdgcn_global_load_lds( \
    (const __attribute__((address_space(1))) void*)(uintptr_t)(const void*)(gp), \
    (__attribute__((address_space(3))) void*)(uintptr_t)(void*)(lp), 16, 0, 0)

// dims
#define NB 2
#define NC 512
#define NH 96
#define NW 320
#define PH 30720      // NH*NW pixels per batch
#define NPIX 61440    // NB*PH
#define NOUT 256

__device__ __forceinline__ unsigned short f2bf(float f) {
    union { float f; unsigned u; } v; v.f = f;
    unsigned r = v.u + 0x7fffu + ((v.u >> 16) & 1u);
    return (unsigned short)(r >> 16);
}

// ---------------- weight cast f32 -> bf16 ----------------
__global__ void k_cast(const float* __restrict__ src, unsigned short* __restrict__ dst, int n) {
    int i = blockIdx.x * 256 + threadIdx.x;
    if (i < n) dst[i] = f2bf(src[i]);
}

// ---------------- small weight transpose [512,512] f32 -> [512,512] bf16 (transposed) ----------------
__global__ __launch_bounds__(256) void k_wtrans(
        const float* __restrict__ wq, const float* __restrict__ wk, const float* __restrict__ wv,
        unsigned short* __restrict__ WqT, unsigned short* __restrict__ WkT, unsigned short* __restrict__ WvT) {
    __shared__ float t[64][65];
    int z = blockIdx.z;
    const float* src = (z == 0) ? wq : (z == 1) ? wk : wv;
    unsigned short* dst = (z == 0) ? WqT : (z == 1) ? WkT : WvT;
    int i0 = blockIdx.y * 64;   // input row (i)
    int c0 = blockIdx.x * 64;   // input col (c)
    int tt = threadIdx.x;
    int r4 = tt >> 4, px = (tt & 15) * 4;
#pragma unroll
    for (int i = 0; i < 4; ++i) {
        int il = i * 16 + r4;
        f32x4 v = *reinterpret_cast<const f32x4*>(src + (size_t)(i0 + il) * 512 + c0 + px);
        t[il][px + 0] = v[0]; t[il][px + 1] = v[1]; t[il][px + 2] = v[2]; t[il][px + 3] = v[3];
    }
    __syncthreads();
    int cc = (tt & 7) * 8, pl0 = tt >> 3;
#pragma unroll
    for (int j = 0; j < 2; ++j) {
        int pl = j * 32 + pl0;
        u16x8 ov;
#pragma unroll
        for (int i = 0; i < 8; ++i) ov[i] = f2bf(t[cc + i][pl]);
        *reinterpret_cast<u16x8*>(dst + (size_t)(c0 + pl) * 512 + i0 + cc) = ov;   // dst[c][i]
    }
}

// ---------------- transpose [b,c,hw] f32 -> [b,hw,c] bf16; right also -> straight bf16 copy ----------------
// tile 64 px x 128 c: transposed writes are 256 B segments (16 lanes x u16x8 per pix row)
__global__ __launch_bounds__(256) void k_transpose(
        const float* __restrict__ L, const float* __restrict__ R,
        unsigned short* __restrict__ Lcl, unsigned short* __restrict__ Rcl,
        unsigned short* __restrict__ Rbf) {
    __shared__ float t[128][65];
    int z = blockIdx.z;                 // which*2 + b
    int b = z & 1, which = z >> 1;
    const float* src = which ? R : L;
    unsigned short* dst = which ? Rcl : Lcl;
    int c0 = blockIdx.y * 128;
    int p0 = blockIdx.x * 64;
    int tt = threadIdx.x;

    int cl16 = tt >> 4;                 // 0..15
    int px = (tt & 15) * 4;
#pragma unroll
    for (int i = 0; i < 8; ++i) {
        int cl = i * 16 + cl16;
        f32x4 v = *reinterpret_cast<const f32x4*>(src + (size_t)(b * NC + c0 + cl) * PH + p0 + px);
        t[cl][px + 0] = v[0];
        t[cl][px + 1] = v[1];
        t[cl][px + 2] = v[2];
        t[cl][px + 3] = v[3];
        if (which) {                    // straight bf16 copy of right (original layout)
            u16x4 sv;
#pragma unroll
            for (int k = 0; k < 4; ++k) sv[k] = f2bf(v[k]);
            *reinterpret_cast<u16x4*>(Rbf + (size_t)(b * NC + c0 + cl) * PH + p0 + px) = sv;
        }
    }
    __syncthreads();

    int cc = (tt & 15) * 8;             // 0..120
    int pl16 = tt >> 4;                 // 0..15
#pragma unroll
    for (int j = 0; j < 4; ++j) {
        int pl = j * 16 + pl16;
        u16x8 ov;
#pragma unroll
        for (int i = 0; i < 8; ++i) ov[i] = f2bf(t[cc + i][pl]);
        *reinterpret_cast<u16x8*>(dst + (size_t)(b * PH + p0 + pl) * NC + c0 + cc) = ov;
    }
}

// ================= staged 128x128-tile GEMM, double-buffered prefetch =================
// MODE 0: T   = Lcl @ Mt^T        D[pix, c2]  bf16   (replaces Q projection)
// MODE 3: y   = concat(Lcl,U) @ concat(w1L,WX)^T, BN+LeakyReLU   D[pix, o] bf16
// MODE 4: out^T = W2 @ Y^T        D[o, pix] -> f32 channels-first (coalesced)
// MODE 5: Mt  = WkT @ WqT^T       D[c2, c1]   bf16 (512x512, 16 blocks)
// MODE 6: WX  = w1O @ WvT^T       D[o2, c]    bf16 (256x512, 8 blocks)
template <int MODE>
__global__ __launch_bounds__(256) void k_gemm(
        const unsigned short* __restrict__ A0,
        const unsigned short* __restrict__ A1,
        const unsigned short* __restrict__ Bb,
        const unsigned short* __restrict__ Bb2,
        unsigned short* __restrict__ Dbf,
        float* __restrict__ Df32,
        const float* __restrict__ g, const float* __restrict__ be,
        const float* __restrict__ mu, const float* __restrict__ va) {
    constexpr int SA = (MODE == 4) ? NOUT : (MODE == 6) ? 1024 : NC;  // A row stride
    constexpr int AOFF = (MODE == 6) ? 512 : 0;                       // A col offset (w1O slice)
    constexpr int SB = (MODE == 3) ? 1024 : (MODE == 4) ? NOUT : NC;
    constexpr int KS = (MODE == 3) ? 32 : (MODE == 4) ? 8 : 16;       // K-steps of 32
    constexpr int NTO = (MODE == 3 || MODE == 4) ? 2 : 4;             // n-tile count
    constexpr int TOT = (MODE == 5) ? 16 : (MODE == 6) ? 8 : ((MODE == 3 || MODE == 4) ? 960 : 1920);

    __shared__ unsigned short Asm[2][128 * 32];
    __shared__ unsigned short Bsm[2][128 * 32];

    int pphys = blockIdx.x;
    int lgc = (pphys & 7) * (TOT / 8) + (pphys >> 3);
    int pixt = lgc / NTO, ot = lgc % NTO;
    const int mbase = ((MODE == 4) ? ot : pixt) * 128;
    const int nbase = ((MODE == 4) ? pixt : ot) * 128;

    const int lane = threadIdx.x & 63, w = threadIdx.x >> 6;
    const int lr = lane & 15, lg = lane >> 4;
    const int wr = w >> 1, wc = w & 1;

    // stage one 128x32 bf16 tile: 512 chunks of 16B; wave w owns chunks [w*128, w*128+128)
    auto stageA = [&](int buf, int kc) {
        const unsigned short* srcA = A0;
        int colOff = kc * 32;
        if constexpr (MODE == 3) {
            if (kc >= 16) { srcA = A1; colOff = (kc - 16) * 32; }
        }
#pragma unroll
        for (int j = 0; j < 2; ++j) {
            int cb = w * 128 + j * 64;           // wave-uniform chunk base
            int c = cb + lane;
            const unsigned short* gp = srcA + (size_t)(mbase + (c >> 2)) * SA + AOFF + colOff + (c & 3) * 8;
            GLOAD_LDS(gp, Asm[buf] + cb * 8);
        }
    };
    auto stageB = [&](int buf, int kc) {
        const unsigned short* srcB = Bb;
        int colOff = kc * 32;
        int sb = SB;
        if constexpr (MODE == 3) {
            if (kc >= 16) { srcB = Bb2; colOff = (kc - 16) * 32; sb = 512; }
        }
#pragma unroll
        for (int j = 0; j < 2; ++j) {
            int cb = w * 128 + j * 64;
            int c = cb + lane;
            const unsigned short* gp = srcB + (size_t)(nbase + (c >> 2)) * sb + colOff + (c & 3) * 8;
            GLOAD_LDS(gp, Bsm[buf] + cb * 8);
        }
    };

    f32x4 acc[4][4] = {};

    stageA(0, 0);
    stageB(0, 0);
    __syncthreads();

    for (int kc = 0; kc < KS; ++kc) {
        int cur = kc & 1;
        if (kc + 1 < KS) {                      // prefetch overlaps this step's MFMA
            stageA(cur ^ 1, kc + 1);
            stageB(cur ^ 1, kc + 1);
        }
        bf16x8 af[4], bfr[4];
#pragma unroll
        for (int i = 0; i < 4; ++i)
            af[i] = *reinterpret_cast<const bf16x8*>(Asm[cur] + (wr * 64 + i * 16 + lr) * 32 + lg * 8);
#pragma unroll
        for (int j = 0; j < 4; ++j)
            bfr[j] = *reinterpret_cast<const bf16x8*>(Bsm[cur] + (wc * 64 + j * 16 + lr) * 32 + lg * 8);
        __builtin_amdgcn_s_setprio(1);
#pragma unroll
        for (int i = 0; i < 4; ++i)
#pragma unroll
            for (int j = 0; j < 4; ++j)
                acc[i][j] = MFMA16(af[i], bfr[j], acc[i][j]);
        __builtin_amdgcn_s_setprio(0);
        __syncthreads();    // drains prefetch (hidden under MFMA) + guards cur-buf reuse
    }

    const int lr4 = lg * 4;
    if constexpr (MODE == 0 || MODE >= 5) {
#pragma unroll
        for (int i = 0; i < 4; ++i)
#pragma unroll
            for (int j = 0; j < 4; ++j) {
                int ocol = nbase + wc * 64 + j * 16 + lr;
#pragma unroll
                for (int r = 0; r < 4; ++r) {
                    int prow = mbase + wr * 64 + i * 16 + lr4 + r;
                    Dbf[(size_t)prow * NC + ocol] = f2bf(acc[i][j][r]);
                }
            }
    } else if constexpr (MODE == 3) {
#pragma unroll
        for (int j = 0; j < 4; ++j) {
            int o = nbase + wc * 64 + j * 16 + lr;
            float sc = g[o] * rsqrtf(va[o] + 1e-5f);
            float sh = be[o] - mu[o] * sc;
#pragma unroll
            for (int i = 0; i < 4; ++i)
#pragma unroll
                for (int r = 0; r < 4; ++r) {
                    int prow = mbase + wr * 64 + i * 16 + lr4 + r;
                    float y = acc[i][j][r] * sc + sh;
                    y = (y >= 0.f) ? y : 0.2f * y;
                    Dbf[(size_t)prow * NOUT + o] = f2bf(y);
                }
        }
    } else {  // MODE 4
#pragma unroll
        for (int j = 0; j < 4; ++j) {
            int pix = nbase + wc * 64 + j * 16 + lr;
            int b = pix / PH, ph = pix % PH;
#pragma unroll
            for (int i = 0; i < 4; ++i)
#pragma unroll
                for (int r = 0; r < 4; ++r) {
                    int o = mbase + wr * 64 + i * 16 + lr4 + r;
                    Df32[((size_t)b * NOUT + o) * PH + ph] = acc[i][j][r];
                }
        }
    }
}

// ---------------- attention: per (b,h), 64 q-rows per block, 3 blocks/CU ----------------
// LDS union (42KB): K-staging dbuf (2x16KB) during QK^T, then P[64][328] (disjoint lifetimes;
// the QK^T-final barrier separates them). V-operand fragments read DIRECTLY from global Rbf
// (lane-contiguous 16B, L2-hot per head) -> no V staging, no PV barriers.
__global__ __launch_bounds__(256, 3) void k_attn(
        const unsigned short* __restrict__ Q, const unsigned short* __restrict__ K,
        const unsigned short* __restrict__ Vb, unsigned short* __restrict__ O) {
    __shared__ unsigned short SH[64 * 328];   // 41984 B union

    int pphys = blockIdx.x;
    int l = (pphys & 7) * 120 + (pphys >> 3);
    int head = l / 5, qt = l % 5;
    int b = head / NH, hh = head % NH;
    int lane = threadIdx.x & 63, w = threadIdx.x >> 6;
    int lr = lane & 15, lg = lane >> 4;
    int rowbase = b * PH + hh * NW;     // pixel index of (b,h, x=0)
    int qrow = rowbase + qt * 64 + w * 16 + lr;

    bf16x8 qf[16];
#pragma unroll
    for (int kc = 0; kc < 16; ++kc)
        qf[kc] = *reinterpret_cast<const bf16x8*>(Q + (size_t)qrow * NC + kc * 32 + lg * 8);

    f32x4 acc[20];
#pragma unroll
    for (int xt = 0; xt < 20; ++xt) acc[xt] = f32x4{0.f, 0.f, 0.f, 0.f};

    // ---- QK^T: 20 K-tiles of 16 rows via global_load_lds, dbuf, 1 barrier/tile ----
    // row r, LDS slot p holds global 16B-slot p^(r&7)  [read swizzle rsw = lr&7]
    auto kstage = [&](int t, int buf) {
#pragma unroll
        for (int j = 0; j < 4; ++j) {
            int r = w * 4 + j;
            const unsigned short* gp = K + (size_t)(rowbase + t * 16 + r) * NC + ((lane ^ (r & 7)) * 8);
            GLOAD_LDS(gp, SH + buf * 8192 + r * 512);
        }
    };
    kstage(0, 0);
    __syncthreads();
#pragma unroll
    for (int t = 0; t < 20; ++t) {
        int buf = t & 1;
        if (t + 1 < 20) kstage(t + 1, buf ^ 1);     // prefetch in flight during MFMA
        int rsw = lr & 7;
        __builtin_amdgcn_s_setprio(1);
#pragma unroll
        for (int kc = 0; kc < 16; ++kc) {
            bf16x8 kf = *reinterpret_cast<const bf16x8*>(
                SH + buf * 8192 + lr * 512 + (((kc * 4 + lg) ^ rsw) * 8));
            acc[t] = MFMA16(qf[kc], kf, acc[t]);
        }
        __builtin_amdgcn_s_setprio(0);
        __syncthreads();    // drains prefetch (hidden under MFMA) + guards buf reuse
    }

    // ---- softmax (rows lg*4+r live on the 16 lanes sharing lg) ----
#pragma unroll
    for (int xt = 0; xt < 20; ++xt)
#pragma unroll
        for (int r = 0; r < 4; ++r) acc[xt][r] *= 0.125f;
    float m[4] = {-1e30f, -1e30f, -1e30f, -1e30f};
#pragma unroll
    for (int xt = 0; xt < 20; ++xt)
#pragma unroll
        for (int r = 0; r < 4; ++r) m[r] = fmaxf(m[r], acc[xt][r]);
#pragma unroll
    for (int mask = 1; mask < 16; mask <<= 1)
#pragma unroll
        for (int r = 0; r < 4; ++r) m[r] = fmaxf(m[r], __shfl_xor(m[r], mask));
    float s4[4] = {0.f, 0.f, 0.f, 0.f};
#pragma unroll
    for (int xt = 0; xt < 20; ++xt)
#pragma unroll
        for (int r = 0; r < 4; ++r) {
            float e = __expf(acc[xt][r] - m[r]);
            acc[xt][r] = e;
            s4[r] += e;
        }
#pragma unroll
    for (int mask = 1; mask < 16; mask <<= 1)
#pragma unroll
        for (int r = 0; r < 4; ++r) s4[r] += __shfl_xor(s4[r], mask);
    // P -> SH union (safe: all K reads completed at the QK^T-final barrier)
#pragma unroll
    for (int xt = 0; xt < 20; ++xt)
#pragma unroll
        for (int r = 0; r < 4; ++r)
            SH[(w * 16 + lg * 4 + r) * 328 + xt * 16 + lr] = f2bf(acc[xt][r]);
    __syncthreads();            // P visible

    // ---- PV: V-fragments direct from global (no LDS, no barriers) ----
    f32x4 oacc[32];
#pragma unroll
    for (int ct = 0; ct < 32; ++ct) oacc[ct] = f32x4{0.f, 0.f, 0.f, 0.f};

#pragma unroll
    for (int s = 0; s < 10; ++s) {
        bf16x8 pf = *reinterpret_cast<const bf16x8*>(SH + (w * 16 + lr) * 328 + s * 32 + lg * 8);
#pragma unroll
        for (int ct = 0; ct < 32; ++ct) {
            bf16x8 vf = *reinterpret_cast<const bf16x8*>(
                Vb + (size_t)(b * NC + ct * 16 + lr) * PH + hh * NW + s * 32 + lg * 8);
            oacc[ct] = MFMA16(pf, vf, oacc[ct]);
        }
    }

#pragma unroll
    for (int ct = 0; ct < 32; ++ct)
#pragma unroll
        for (int r = 0; r < 4; ++r) {
            int prow = rowbase + qt * 64 + w * 16 + lg * 4 + r;
            O[(size_t)prow * NC + ct * 16 + lr] = f2bf(oacc[ct][r] / s4[r]);
        }
}

extern "C" void kernel_launch(void* const* d_in, const int* in_sizes, int n_in,
                              void* d_out, int out_size, void* d_ws, size_t ws_size,
                              hipStream_t stream) {
    const float* left  = (const float*)d_in[0];
    const float* right = (const float*)d_in[1];
    const float* wq = (const float*)d_in[2];
    const float* wk = (const float*)d_in[3];
    const float* wv = (const float*)d_in[4];
    const float* w1 = (const float*)d_in[5];
    const float* bn_g = (const float*)d_in[6];
    const float* bn_b = (const float*)d_in[7];
    const float* bn_m = (const float*)d_in[8];
    const float* bn_v = (const float*)d_in[9];
    const float* w2 = (const float*)d_in[10];
    float* out = (float*)d_out;

    size_t off = 0;
    auto alloc = [&](size_t bytes) -> void* {
        void* p = (char*)d_ws + off;
        off += (bytes + 255) & ~(size_t)255;
        return p;
    };
    const size_t clb = (size_t)NPIX * NC * 2;        // 62.9 MB
    unsigned short* Lcl = (unsigned short*)alloc(clb);
    unsigned short* Rcl = (unsigned short*)alloc(clb);
    unsigned short* Rbf = (unsigned short*)alloc(clb);
    unsigned short* Qb  = (unsigned short*)alloc(clb);   // T, then aliased by Yb
    unsigned short* Ub  = (unsigned short*)alloc(clb);   // attn @ Rbf
    unsigned short* WqT = (unsigned short*)alloc((size_t)NC * NC * 2);
    unsigned short* WkT = (unsigned short*)alloc((size_t)NC * NC * 2);
    unsigned short* WvT = (unsigned short*)alloc((size_t)NC * NC * 2);
    unsigned short* Mt  = (unsigned short*)alloc((size_t)NC * NC * 2);
    unsigned short* WX  = (unsigned short*)alloc((size_t)NOUT * NC * 2);
    unsigned short* W1b = (unsigned short*)alloc((size_t)NOUT * 1024 * 2);
    unsigned short* W2b = (unsigned short*)alloc((size_t)NOUT * NOUT * 2);
    unsigned short* Yb = Qb;    // y aliases Qb (T dead after attention)

    k_cast<<<dim3((NOUT * 1024 + 255) / 256), 256, 0, stream>>>(w1, W1b, NOUT * 1024);
    k_cast<<<dim3((NOUT * NOUT + 255) / 256), 256, 0, stream>>>(w2, W2b, NOUT * NOUT);

    // WqT/WkT/WvT [c][i] bf16
    k_wtrans<<<dim3(8, 8, 3), 256, 0, stream>>>(wq, wk, wv, WqT, WkT, WvT);

    // Lcl/Rcl channels-last + Rbf straight bf16 copy of right (64px x 128c tiles)
    k_transpose<<<dim3(PH / 64, NC / 128, 4), 256, 0, stream>>>(left, right, Lcl, Rcl, Rbf);

    // Mt[c2][c1] = sum_i wk[i,c2] wq[i,c1]   (B-operand for T-GEMM)
    k_gemm<5><<<dim3(16), 256, 0, stream>>>(WkT, nullptr, WqT, nullptr, Mt, nullptr, nullptr, nullptr, nullptr, nullptr);
    // WX[o2][c] = sum_o w1[o2,512+o] wv[o,c]
    k_gemm<6><<<dim3(8), 256, 0, stream>>>(W1b, nullptr, WvT, nullptr, WX, nullptr, nullptr, nullptr, nullptr, nullptr);

    // T = Lcl @ Mt^T  [61440, 512]
    k_gemm<0><<<dim3(1920), 256, 0, stream>>>(Lcl, nullptr, Mt, nullptr, Qb, nullptr, nullptr, nullptr, nullptr, nullptr);

    // attn: dots = T @ Rcl^T; U = softmax(dots) @ Rbf
    k_attn<<<dim3(960), 256, 0, stream>>>(Qb, Rcl, Rbf, Ub);

    // y = concat(Lcl, U) @ concat(w1L, WX)^T + BN + LeakyReLU
    k_gemm<3><<<dim3(960), 256, 0, stream>>>(Lcl, Ub, W1b, WX, Yb, nullptr, bn_g, bn_b, bn_m, bn_v);

    // out^T = W2 @ Y^T, f32 channels-first
    k_gemm<4><<<dim3(960), 256, 0, stream>>>(W2b, nullptr, Yb, nullptr, nullptr, out, nullptr, nullptr, nullptr, nullptr);
}

// Round 14
// 542.269 us; speedup vs baseline: 1.3909x; 1.3909x over previous
//
#include <hip/hip_runtime.h>

typedef __bf16 bf16x8 __attribute__((ext_vector_type(8)));
typedef float f32x4 __attribute__((ext_vector_type(4)));
typedef unsigned short u16x8 __attribute__((ext_vector_type(8)));
typedef unsigned short u16x4 __attribute__((ext_vector_type(4)));

#define MFMA16(a, b, c) __builtin_amdgcn_mfma_f32_16x16x32_bf16((a), (b), (c), 0, 0, 0)
#define GLOAD_LDS(gp, lp) __builtin_amdgcn_global_load_lds( \
    (const __attribute__((address_space(1))) void*)(uintptr_t)(const void*)(gp), \
    (__attribute__((address_space(3))) void*)(uintptr_t)(void*)(lp), 16, 0, 0)

// dims
#define NB 2
#define NC 512
#define NH 96
#define NW 320
#define PH 30720      // NH*NW pixels per batch
#define NPIX 61440    // NB*PH
#define NOUT 256

__device__ __forceinline__ unsigned short f2bf(float f) {
    union { float f; unsigned u; } v; v.f = f;
    unsigned r = v.u + 0x7fffu + ((v.u >> 16) & 1u);
    return (unsigned short)(r >> 16);
}

// ---------------- weight cast f32 -> bf16 ----------------
__global__ void k_cast(const float* __restrict__ src, unsigned short* __restrict__ dst, int n) {
    int i = blockIdx.x * 256 + threadIdx.x;
    if (i < n) dst[i] = f2bf(src[i]);
}

// ---------------- small weight transpose [512,512] f32 -> [512,512] bf16 (transposed) ----------------
__global__ __launch_bounds__(256) void k_wtrans(
        const float* __restrict__ wq, const float* __restrict__ wk, const float* __restrict__ wv,
        unsigned short* __restrict__ WqT, unsigned short* __restrict__ WkT, unsigned short* __restrict__ WvT) {
    __shared__ float t[64][65];
    int z = blockIdx.z;
    const float* src = (z == 0) ? wq : (z == 1) ? wk : wv;
    unsigned short* dst = (z == 0) ? WqT : (z == 1) ? WkT : WvT;
    int i0 = blockIdx.y * 64;   // input row (i)
    int c0 = blockIdx.x * 64;   // input col (c)
    int tt = threadIdx.x;
    int r4 = tt >> 4, px = (tt & 15) * 4;
#pragma unroll
    for (int i = 0; i < 4; ++i) {
        int il = i * 16 + r4;
        f32x4 v = *reinterpret_cast<const f32x4*>(src + (size_t)(i0 + il) * 512 + c0 + px);
        t[il][px + 0] = v[0]; t[il][px + 1] = v[1]; t[il][px + 2] = v[2]; t[il][px + 3] = v[3];
    }
    __syncthreads();
    int cc = (tt & 7) * 8, pl0 = tt >> 3;
#pragma unroll
    for (int j = 0; j < 2; ++j) {
        int pl = j * 32 + pl0;
        u16x8 ov;
#pragma unroll
        for (int i = 0; i < 8; ++i) ov[i] = f2bf(t[cc + i][pl]);
        *reinterpret_cast<u16x8*>(dst + (size_t)(c0 + pl) * 512 + i0 + cc) = ov;   // dst[c][i]
    }
}

// ---------------- transpose [b,c,hw] f32 -> [b,hw,c] bf16; right also -> straight bf16 copy ----------------
// tile 64 px x 128 c: transposed writes are 256 B segments (16 lanes x u16x8 per pix row)
__global__ __launch_bounds__(256) void k_transpose(
        const float* __restrict__ L, const float* __restrict__ R,
        unsigned short* __restrict__ Lcl, unsigned short* __restrict__ Rcl,
        unsigned short* __restrict__ Rbf) {
    __shared__ float t[128][65];
    int z = blockIdx.z;                 // which*2 + b
    int b = z & 1, which = z >> 1;
    const float* src = which ? R : L;
    unsigned short* dst = which ? Rcl : Lcl;
    int c0 = blockIdx.y * 128;
    int p0 = blockIdx.x * 64;
    int tt = threadIdx.x;

    int cl16 = tt >> 4;                 // 0..15
    int px = (tt & 15) * 4;
#pragma unroll
    for (int i = 0; i < 8; ++i) {
        int cl = i * 16 + cl16;
        f32x4 v = *reinterpret_cast<const f32x4*>(src + (size_t)(b * NC + c0 + cl) * PH + p0 + px);
        t[cl][px + 0] = v[0];
        t[cl][px + 1] = v[1];
        t[cl][px + 2] = v[2];
        t[cl][px + 3] = v[3];
        if (which) {                    // straight bf16 copy of right (original layout)
            u16x4 sv;
#pragma unroll
            for (int k = 0; k < 4; ++k) sv[k] = f2bf(v[k]);
            *reinterpret_cast<u16x4*>(Rbf + (size_t)(b * NC + c0 + cl) * PH + p0 + px) = sv;
        }
    }
    __syncthreads();

    int cc = (tt & 15) * 8;             // 0..120
    int pl16 = tt >> 4;                 // 0..15
#pragma unroll
    for (int j = 0; j < 4; ++j) {
        int pl = j * 16 + pl16;
        u16x8 ov;
#pragma unroll
        for (int i = 0; i < 8; ++i) ov[i] = f2bf(t[cc + i][pl]);
        *reinterpret_cast<u16x8*>(dst + (size_t)(b * PH + p0 + pl) * NC + c0 + cc) = ov;
    }
}

// ================= staged 128x128-tile GEMM, double-buffered prefetch =================
// MODE 0: T   = Lcl @ Mt^T        D[pix, c2]  bf16   (replaces Q projection)
// MODE 3: y   = concat(Lcl,U) @ concat(w1L,WX)^T, BN+LeakyReLU   D[pix, o] bf16
// MODE 4: out^T = W2 @ Y^T        D[o, pix] -> f32 channels-first (coalesced)
// MODE 5: Mt  = WkT @ WqT^T       D[c2, c1]   bf16 (512x512, 16 blocks)
// MODE 6: WX  = w1O @ WvT^T       D[o2, c]    bf16 (256x512, 8 blocks)
template <int MODE>
__global__ __launch_bounds__(256) void k_gemm(
        const unsigned short* __restrict__ A0,
        const unsigned short* __restrict__ A1,
        const unsigned short* __restrict__ Bb,
        const unsigned short* __restrict__ Bb2,
        unsigned short* __restrict__ Dbf,
        float* __restrict__ Df32,
        const float* __restrict__ g, const float* __restrict__ be,
        const float* __restrict__ mu, const float* __restrict__ va) {
    constexpr int SA = (MODE == 4) ? NOUT : (MODE == 6) ? 1024 : NC;  // A row stride
    constexpr int AOFF = (MODE == 6) ? 512 : 0;                       // A col offset (w1O slice)
    constexpr int SB = (MODE == 3) ? 1024 : (MODE == 4) ? NOUT : NC;
    constexpr int KS = (MODE == 3) ? 32 : (MODE == 4) ? 8 : 16;       // K-steps of 32
    constexpr int NTO = (MODE == 3 || MODE == 4) ? 2 : 4;             // n-tile count
    constexpr int TOT = (MODE == 5) ? 16 : (MODE == 6) ? 8 : ((MODE == 3 || MODE == 4) ? 960 : 1920);

    __shared__ unsigned short Asm[2][128 * 32];
    __shared__ unsigned short Bsm[2][128 * 32];

    int pphys = blockIdx.x;
    int lgc = (pphys & 7) * (TOT / 8) + (pphys >> 3);
    int pixt = lgc / NTO, ot = lgc % NTO;
    const int mbase = ((MODE == 4) ? ot : pixt) * 128;
    const int nbase = ((MODE == 4) ? pixt : ot) * 128;

    const int lane = threadIdx.x & 63, w = threadIdx.x >> 6;
    const int lr = lane & 15, lg = lane >> 4;
    const int wr = w >> 1, wc = w & 1;

    // stage one 128x32 bf16 tile: 512 chunks of 16B; wave w owns chunks [w*128, w*128+128)
    auto stageA = [&](int buf, int kc) {
        const unsigned short* srcA = A0;
        int colOff = kc * 32;
        if constexpr (MODE == 3) {
            if (kc >= 16) { srcA = A1; colOff = (kc - 16) * 32; }
        }
#pragma unroll
        for (int j = 0; j < 2; ++j) {
            int cb = w * 128 + j * 64;           // wave-uniform chunk base
            int c = cb + lane;
            const unsigned short* gp = srcA + (size_t)(mbase + (c >> 2)) * SA + AOFF + colOff + (c & 3) * 8;
            GLOAD_LDS(gp, Asm[buf] + cb * 8);
        }
    };
    auto stageB = [&](int buf, int kc) {
        const unsigned short* srcB = Bb;
        int colOff = kc * 32;
        int sb = SB;
        if constexpr (MODE == 3) {
            if (kc >= 16) { srcB = Bb2; colOff = (kc - 16) * 32; sb = 512; }
        }
#pragma unroll
        for (int j = 0; j < 2; ++j) {
            int cb = w * 128 + j * 64;
            int c = cb + lane;
            const unsigned short* gp = srcB + (size_t)(nbase + (c >> 2)) * sb + colOff + (c & 3) * 8;
            GLOAD_LDS(gp, Bsm[buf] + cb * 8);
        }
    };

    f32x4 acc[4][4] = {};

    stageA(0, 0);
    stageB(0, 0);
    __syncthreads();

    for (int kc = 0; kc < KS; ++kc) {
        int cur = kc & 1;
        if (kc + 1 < KS) {                      // prefetch overlaps this step's MFMA
            stageA(cur ^ 1, kc + 1);
            stageB(cur ^ 1, kc + 1);
        }
        bf16x8 af[4], bfr[4];
#pragma unroll
        for (int i = 0; i < 4; ++i)
            af[i] = *reinterpret_cast<const bf16x8*>(Asm[cur] + (wr * 64 + i * 16 + lr) * 32 + lg * 8);
#pragma unroll
        for (int j = 0; j < 4; ++j)
            bfr[j] = *reinterpret_cast<const bf16x8*>(Bsm[cur] + (wc * 64 + j * 16 + lr) * 32 + lg * 8);
        __builtin_amdgcn_s_setprio(1);
#pragma unroll
        for (int i = 0; i < 4; ++i)
#pragma unroll
            for (int j = 0; j < 4; ++j)
                acc[i][j] = MFMA16(af[i], bfr[j], acc[i][j]);
        __builtin_amdgcn_s_setprio(0);
        __syncthreads();    // drains prefetch (hidden under MFMA) + guards cur-buf reuse
    }

    const int lr4 = lg * 4;
    if constexpr (MODE == 0 || MODE >= 5) {
#pragma unroll
        for (int i = 0; i < 4; ++i)
#pragma unroll
            for (int j = 0; j < 4; ++j) {
                int ocol = nbase + wc * 64 + j * 16 + lr;
#pragma unroll
                for (int r = 0; r < 4; ++r) {
                    int prow = mbase + wr * 64 + i * 16 + lr4 + r;
                    Dbf[(size_t)prow * NC + ocol] = f2bf(acc[i][j][r]);
                }
            }
    } else if constexpr (MODE == 3) {
#pragma unroll
        for (int j = 0; j < 4; ++j) {
            int o = nbase + wc * 64 + j * 16 + lr;
            float sc = g[o] * rsqrtf(va[o] + 1e-5f);
            float sh = be[o] - mu[o] * sc;
#pragma unroll
            for (int i = 0; i < 4; ++i)
#pragma unroll
                for (int r = 0; r < 4; ++r) {
                    int prow = mbase + wr * 64 + i * 16 + lr4 + r;
                    float y = acc[i][j][r] * sc + sh;
                    y = (y >= 0.f) ? y : 0.2f * y;
                    Dbf[(size_t)prow * NOUT + o] = f2bf(y);
                }
        }
    } else {  // MODE 4
#pragma unroll
        for (int j = 0; j < 4; ++j) {
            int pix = nbase + wc * 64 + j * 16 + lr;
            int b = pix / PH, ph = pix % PH;
#pragma unroll
            for (int i = 0; i < 4; ++i)
#pragma unroll
                for (int r = 0; r < 4; ++r) {
                    int o = mbase + wr * 64 + i * 16 + lr4 + r;
                    Df32[((size_t)b * NOUT + o) * PH + ph] = acc[i][j][r];
                }
        }
    }
}

// ---------------- attention: per (b,h), 64 q-rows per block ----------------
// LDS union (42KB): K-staging dbuf (2x16KB) during QK^T, then P[64][328] (disjoint
// lifetimes; the QK^T-final barrier separates them). V-operand fragments read DIRECTLY
// from global Rbf (lane-contiguous 16B, L2-hot per head) -> no V staging, no PV barriers.
// launch_bounds (256,2): full 256-VGPR cap — the (256,3) variant spilled (r11/r13 lesson).
__global__ __launch_bounds__(256, 2) void k_attn(
        const unsigned short* __restrict__ Q, const unsigned short* __restrict__ K,
        const unsigned short* __restrict__ Vb, unsigned short* __restrict__ O) {
    __shared__ unsigned short SH[64 * 328];   // 41984 B union

    int pphys = blockIdx.x;
    int l = (pphys & 7) * 120 + (pphys >> 3);
    int head = l / 5, qt = l % 5;
    int b = head / NH, hh = head % NH;
    int lane = threadIdx.x & 63, w = threadIdx.x >> 6;
    int lr = lane & 15, lg = lane >> 4;
    int rowbase = b * PH + hh * NW;     // pixel index of (b,h, x=0)
    int qrow = rowbase + qt * 64 + w * 16 + lr;

    bf16x8 qf[16];
#pragma unroll
    for (int kc = 0; kc < 16; ++kc)
        qf[kc] = *reinterpret_cast<const bf16x8*>(Q + (size_t)qrow * NC + kc * 32 + lg * 8);

    f32x4 acc[20];
#pragma unroll
    for (int xt = 0; xt < 20; ++xt) acc[xt] = f32x4{0.f, 0.f, 0.f, 0.f};

    // ---- QK^T: 20 K-tiles of 16 rows via global_load_lds, dbuf, 1 barrier/tile ----
    // row r, LDS slot p holds global 16B-slot p^(r&7)  [read swizzle rsw = lr&7]
    auto kstage = [&](int t, int buf) {
#pragma unroll
        for (int j = 0; j < 4; ++j) {
            int r = w * 4 + j;
            const unsigned short* gp = K + (size_t)(rowbase + t * 16 + r) * NC + ((lane ^ (r & 7)) * 8);
            GLOAD_LDS(gp, SH + buf * 8192 + r * 512);
        }
    };
    kstage(0, 0);
    __syncthreads();
#pragma unroll
    for (int t = 0; t < 20; ++t) {
        int buf = t & 1;
        if (t + 1 < 20) kstage(t + 1, buf ^ 1);     // prefetch in flight during MFMA
        int rsw = lr & 7;
        __builtin_amdgcn_s_setprio(1);
#pragma unroll
        for (int kc = 0; kc < 16; ++kc) {
            bf16x8 kf = *reinterpret_cast<const bf16x8*>(
                SH + buf * 8192 + lr * 512 + (((kc * 4 + lg) ^ rsw) * 8));
            acc[t] = MFMA16(qf[kc], kf, acc[t]);
        }
        __builtin_amdgcn_s_setprio(0);
        __syncthreads();    // drains prefetch (hidden under MFMA) + guards buf reuse
    }

    // ---- softmax (rows lg*4+r live on the 16 lanes sharing lg) ----
#pragma unroll
    for (int xt = 0; xt < 20; ++xt)
#pragma unroll
        for (int r = 0; r < 4; ++r) acc[xt][r] *= 0.125f;
    float m[4] = {-1e30f, -1e30f, -1e30f, -1e30f};
#pragma unroll
    for (int xt = 0; xt < 20; ++xt)
#pragma unroll
        for (int r = 0; r < 4; ++r) m[r] = fmaxf(m[r], acc[xt][r]);
#pragma unroll
    for (int mask = 1; mask < 16; mask <<= 1)
#pragma unroll
        for (int r = 0; r < 4; ++r) m[r] = fmaxf(m[r], __shfl_xor(m[r], mask));
    float s4[4] = {0.f, 0.f, 0.f, 0.f};
#pragma unroll
    for (int xt = 0; xt < 20; ++xt)
#pragma unroll
        for (int r = 0; r < 4; ++r) {
            float e = __expf(acc[xt][r] - m[r]);
            acc[xt][r] = e;
            s4[r] += e;
        }
#pragma unroll
    for (int mask = 1; mask < 16; mask <<= 1)
#pragma unroll
        for (int r = 0; r < 4; ++r) s4[r] += __shfl_xor(s4[r], mask);
    // P -> SH union (safe: all K reads completed at the QK^T-final barrier)
#pragma unroll
    for (int xt = 0; xt < 20; ++xt)
#pragma unroll
        for (int r = 0; r < 4; ++r)
            SH[(w * 16 + lg * 4 + r) * 328 + xt * 16 + lr] = f2bf(acc[xt][r]);
    __syncthreads();            // P visible

    // ---- PV: V-fragments direct from global (no LDS, no barriers) ----
    f32x4 oacc[32];
#pragma unroll
    for (int ct = 0; ct < 32; ++ct) oacc[ct] = f32x4{0.f, 0.f, 0.f, 0.f};

#pragma unroll
    for (int s = 0; s < 10; ++s) {
        bf16x8 pf = *reinterpret_cast<const bf16x8*>(SH + (w * 16 + lr) * 328 + s * 32 + lg * 8);
#pragma unroll
        for (int ct = 0; ct < 32; ++ct) {
            bf16x8 vf = *reinterpret_cast<const bf16x8*>(
                Vb + (size_t)(b * NC + ct * 16 + lr) * PH + hh * NW + s * 32 + lg * 8);
            oacc[ct] = MFMA16(pf, vf, oacc[ct]);
        }
    }

#pragma unroll
    for (int ct = 0; ct < 32; ++ct)
#pragma unroll
        for (int r = 0; r < 4; ++r) {
            int prow = rowbase + qt * 64 + w * 16 + lg * 4 + r;
            O[(size_t)prow * NC + ct * 16 + lr] = f2bf(oacc[ct][r] / s4[r]);
        }
}

extern "C" void kernel_launch(void* const* d_in, const int* in_sizes, int n_in,
                              void* d_out, int out_size, void* d_ws, size_t ws_size,
                              hipStream_t stream) {
    const float* left  = (const float*)d_in[0];
    const float* right = (const float*)d_in[1];
    const float* wq = (const float*)d_in[2];
    const float* wk = (const float*)d_in[3];
    const float* wv = (const float*)d_in[4];
    const float* w1 = (const float*)d_in[5];
    const float* bn_g = (const float*)d_in[6];
    const float* bn_b = (const float*)d_in[7];
    const float* bn_m = (const float*)d_in[8];
    const float* bn_v = (const float*)d_in[9];
    const float* w2 = (const float*)d_in[10];
    float* out = (float*)d_out;

    size_t off = 0;
    auto alloc = [&](size_t bytes) -> void* {
        void* p = (char*)d_ws + off;
        off += (bytes + 255) & ~(size_t)255;
        return p;
    };
    const size_t clb = (size_t)NPIX * NC * 2;        // 62.9 MB
    unsigned short* Lcl = (unsigned short*)alloc(clb);
    unsigned short* Rcl = (unsigned short*)alloc(clb);
    unsigned short* Rbf = (unsigned short*)alloc(clb);
    unsigned short* Qb  = (unsigned short*)alloc(clb);   // T, then aliased by Yb
    unsigned short* Ub  = (unsigned short*)alloc(clb);   // attn @ Rbf
    unsigned short* WqT = (unsigned short*)alloc((size_t)NC * NC * 2);
    unsigned short* WkT = (unsigned short*)alloc((size_t)NC * NC * 2);
    unsigned short* WvT = (unsigned short*)alloc((size_t)NC * NC * 2);
    unsigned short* Mt  = (unsigned short*)alloc((size_t)NC * NC * 2);
    unsigned short* WX  = (unsigned short*)alloc((size_t)NOUT * NC * 2);
    unsigned short* W1b = (unsigned short*)alloc((size_t)NOUT * 1024 * 2);
    unsigned short* W2b = (unsigned short*)alloc((size_t)NOUT * NOUT * 2);
    unsigned short* Yb = Qb;    // y aliases Qb (T dead after attention)

    k_cast<<<dim3((NOUT * 1024 + 255) / 256), 256, 0, stream>>>(w1, W1b, NOUT * 1024);
    k_cast<<<dim3((NOUT * NOUT + 255) / 256), 256, 0, stream>>>(w2, W2b, NOUT * NOUT);

    // WqT/WkT/WvT [c][i] bf16
    k_wtrans<<<dim3(8, 8, 3), 256, 0, stream>>>(wq, wk, wv, WqT, WkT, WvT);

    // Lcl/Rcl channels-last + Rbf straight bf16 copy of right (64px x 128c tiles)
    k_transpose<<<dim3(PH / 64, NC / 128, 4), 256, 0, stream>>>(left, right, Lcl, Rcl, Rbf);

    // Mt[c2][c1] = sum_i wk[i,c2] wq[i,c1]   (B-operand for T-GEMM)
    k_gemm<5><<<dim3(16), 256, 0, stream>>>(WkT, nullptr, WqT, nullptr, Mt, nullptr, nullptr, nullptr, nullptr, nullptr);
    // WX[o2][c] = sum_o w1[o2,512+o] wv[o,c]
    k_gemm<6><<<dim3(8), 256, 0, stream>>>(W1b, nullptr, WvT, nullptr, WX, nullptr, nullptr, nullptr, nullptr, nullptr);

    // T = Lcl @ Mt^T  [61440, 512]
    k_gemm<0><<<dim3(1920), 256, 0, stream>>>(Lcl, nullptr, Mt, nullptr, Qb, nullptr, nullptr, nullptr, nullptr, nullptr);

    // attn: dots = T @ Rcl^T; U = softmax(dots) @ Rbf
    k_attn<<<dim3(960), 256, 0, stream>>>(Qb, Rcl, Rbf, Ub);

    // y = concat(Lcl, U) @ concat(w1L, WX)^T + BN + LeakyReLU
    k_gemm<3><<<dim3(960), 256, 0, stream>>>(Lcl, Ub, W1b, WX, Yb, nullptr, bn_g, bn_b, bn_m, bn_v);

    // out^T = W2 @ Y^T, f32 channels-first
    k_gemm<4><<<dim3(960), 256, 0, stream>>>(W2b, nullptr, Yb, nullptr, nullptr, out, nullptr, nullptr, nullptr, nullptr);
}

// Round 15
// 350.020 us; speedup vs baseline: 2.1548x; 1.5493x over previous
//
#include <hip/hip_runtime.h>

typedef __bf16 bf16x8 __attribute__((ext_vector_type(8)));
typedef float f32x4 __attribute__((ext_vector_type(4)));
typedef unsigned short u16x8 __attribute__((ext_vector_type(8)));
typedef unsigned short u16x4 __attribute__((ext_vector_type(4)));

#define MFMA16(a, b, c) __builtin_amdgcn_mfma_f32_16x16x32_bf16((a), (b), (c), 0, 0, 0)
#define GLOAD_LDS(gp, lp) __builtin_amdgcn_global_load_lds( \
    (const __attribute__((address_space(1))) void*)(uintptr_t)(const void*)(gp), \
    (__attribute__((address_space(3))) void*)(uintptr_t)(void*)(lp), 16, 0, 0)

// dims
#define NB 2
#define NC 512
#define NH 96
#define NW 320
#define PH 30720      // NH*NW pixels per batch
#define NPIX 61440    // NB*PH
#define NOUT 256

__device__ __forceinline__ unsigned short f2bf(float f) {
    union { float f; unsigned u; } v; v.f = f;
    unsigned r = v.u + 0x7fffu + ((v.u >> 16) & 1u);
    return (unsigned short)(r >> 16);
}

// ---------------- weight cast f32 -> bf16 ----------------
__global__ void k_cast(const float* __restrict__ src, unsigned short* __restrict__ dst, int n) {
    int i = blockIdx.x * 256 + threadIdx.x;
    if (i < n) dst[i] = f2bf(src[i]);
}

// ---------------- small weight transpose [512,512] f32 -> [512,512] bf16 (transposed) ----------------
__global__ __launch_bounds__(256) void k_wtrans(
        const float* __restrict__ wq, const float* __restrict__ wk, const float* __restrict__ wv,
        unsigned short* __restrict__ WqT, unsigned short* __restrict__ WkT, unsigned short* __restrict__ WvT) {
    __shared__ float t[64][65];
    int z = blockIdx.z;
    const float* src = (z == 0) ? wq : (z == 1) ? wk : wv;
    unsigned short* dst = (z == 0) ? WqT : (z == 1) ? WkT : WvT;
    int i0 = blockIdx.y * 64;   // input row (i)
    int c0 = blockIdx.x * 64;   // input col (c)
    int tt = threadIdx.x;
    int r4 = tt >> 4, px = (tt & 15) * 4;
#pragma unroll
    for (int i = 0; i < 4; ++i) {
        int il = i * 16 + r4;
        f32x4 v = *reinterpret_cast<const f32x4*>(src + (size_t)(i0 + il) * 512 + c0 + px);
        t[il][px + 0] = v[0]; t[il][px + 1] = v[1]; t[il][px + 2] = v[2]; t[il][px + 3] = v[3];
    }
    __syncthreads();
    int cc = (tt & 7) * 8, pl0 = tt >> 3;
#pragma unroll
    for (int j = 0; j < 2; ++j) {
        int pl = j * 32 + pl0;
        u16x8 ov;
#pragma unroll
        for (int i = 0; i < 8; ++i) ov[i] = f2bf(t[cc + i][pl]);
        *reinterpret_cast<u16x8*>(dst + (size_t)(c0 + pl) * 512 + i0 + cc) = ov;   // dst[c][i]
    }
}

// ---------------- transpose [b,c,hw] f32 -> [b,hw,c] bf16; right also -> straight bf16 copy ----------------
// tile 64 px x 128 c: transposed writes are 256 B segments (16 lanes x u16x8 per pix row)
__global__ __launch_bounds__(256) void k_transpose(
        const float* __restrict__ L, const float* __restrict__ R,
        unsigned short* __restrict__ Lcl, unsigned short* __restrict__ Rcl,
        unsigned short* __restrict__ Rbf) {
    __shared__ float t[128][65];
    int z = blockIdx.z;                 // which*2 + b
    int b = z & 1, which = z >> 1;
    const float* src = which ? R : L;
    unsigned short* dst = which ? Rcl : Lcl;
    int c0 = blockIdx.y * 128;
    int p0 = blockIdx.x * 64;
    int tt = threadIdx.x;

    int cl16 = tt >> 4;                 // 0..15
    int px = (tt & 15) * 4;
#pragma unroll
    for (int i = 0; i < 8; ++i) {
        int cl = i * 16 + cl16;
        f32x4 v = *reinterpret_cast<const f32x4*>(src + (size_t)(b * NC + c0 + cl) * PH + p0 + px);
        t[cl][px + 0] = v[0];
        t[cl][px + 1] = v[1];
        t[cl][px + 2] = v[2];
        t[cl][px + 3] = v[3];
        if (which) {                    // straight bf16 copy of right (original layout)
            u16x4 sv;
#pragma unroll
            for (int k = 0; k < 4; ++k) sv[k] = f2bf(v[k]);
            *reinterpret_cast<u16x4*>(Rbf + (size_t)(b * NC + c0 + cl) * PH + p0 + px) = sv;
        }
    }
    __syncthreads();

    int cc = (tt & 15) * 8;             // 0..120
    int pl16 = tt >> 4;                 // 0..15
#pragma unroll
    for (int j = 0; j < 4; ++j) {
        int pl = j * 16 + pl16;
        u16x8 ov;
#pragma unroll
        for (int i = 0; i < 8; ++i) ov[i] = f2bf(t[cc + i][pl]);
        *reinterpret_cast<u16x8*>(dst + (size_t)(b * PH + p0 + pl) * NC + c0 + cc) = ov;
    }
}

// ================= staged 128x128-tile GEMM, double-buffered prefetch =================
// MODE 0: T   = Lcl @ Mt^T        D[pix, c2]  bf16   (replaces Q projection)
// MODE 3: y   = concat(Lcl,U) @ concat(w1L,WX)^T, BN+LeakyReLU   D[pix, o] bf16
// MODE 4: out^T = W2 @ Y^T        D[o, pix] -> f32 channels-first (coalesced)
// MODE 5: Mt  = WkT @ WqT^T       D[c2, c1]   bf16 (512x512, 16 blocks)
// MODE 6: WX  = w1O @ WvT^T       D[o2, c]    bf16 (256x512, 8 blocks)
template <int MODE>
__global__ __launch_bounds__(256) void k_gemm(
        const unsigned short* __restrict__ A0,
        const unsigned short* __restrict__ A1,
        const unsigned short* __restrict__ Bb,
        const unsigned short* __restrict__ Bb2,
        unsigned short* __restrict__ Dbf,
        float* __restrict__ Df32,
        const float* __restrict__ g, const float* __restrict__ be,
        const float* __restrict__ mu, const float* __restrict__ va) {
    constexpr int SA = (MODE == 4) ? NOUT : (MODE == 6) ? 1024 : NC;  // A row stride
    constexpr int AOFF = (MODE == 6) ? 512 : 0;                       // A col offset (w1O slice)
    constexpr int SB = (MODE == 3) ? 1024 : (MODE == 4) ? NOUT : NC;
    constexpr int KS = (MODE == 3) ? 32 : (MODE == 4) ? 8 : 16;       // K-steps of 32
    constexpr int NTO = (MODE == 3 || MODE == 4) ? 2 : 4;             // n-tile count
    constexpr int TOT = (MODE == 5) ? 16 : (MODE == 6) ? 8 : ((MODE == 3 || MODE == 4) ? 960 : 1920);

    __shared__ unsigned short Asm[2][128 * 32];
    __shared__ unsigned short Bsm[2][128 * 32];

    int pphys = blockIdx.x;
    int lgc = (pphys & 7) * (TOT / 8) + (pphys >> 3);
    int pixt = lgc / NTO, ot = lgc % NTO;
    const int mbase = ((MODE == 4) ? ot : pixt) * 128;
    const int nbase = ((MODE == 4) ? pixt : ot) * 128;

    const int lane = threadIdx.x & 63, w = threadIdx.x >> 6;
    const int lr = lane & 15, lg = lane >> 4;
    const int wr = w >> 1, wc = w & 1;

    // stage one 128x32 bf16 tile: 512 chunks of 16B; wave w owns chunks [w*128, w*128+128)
    auto stageA = [&](int buf, int kc) {
        const unsigned short* srcA = A0;
        int colOff = kc * 32;
        if constexpr (MODE == 3) {
            if (kc >= 16) { srcA = A1; colOff = (kc - 16) * 32; }
        }
#pragma unroll
        for (int j = 0; j < 2; ++j) {
            int cb = w * 128 + j * 64;           // wave-uniform chunk base
            int c = cb + lane;
            const unsigned short* gp = srcA + (size_t)(mbase + (c >> 2)) * SA + AOFF + colOff + (c & 3) * 8;
            GLOAD_LDS(gp, Asm[buf] + cb * 8);
        }
    };
    auto stageB = [&](int buf, int kc) {
        const unsigned short* srcB = Bb;
        int colOff = kc * 32;
        int sb = SB;
        if constexpr (MODE == 3) {
            if (kc >= 16) { srcB = Bb2; colOff = (kc - 16) * 32; sb = 512; }
        }
#pragma unroll
        for (int j = 0; j < 2; ++j) {
            int cb = w * 128 + j * 64;
            int c = cb + lane;
            const unsigned short* gp = srcB + (size_t)(nbase + (c >> 2)) * sb + colOff + (c & 3) * 8;
            GLOAD_LDS(gp, Bsm[buf] + cb * 8);
        }
    };

    f32x4 acc[4][4] = {};

    stageA(0, 0);
    stageB(0, 0);
    __syncthreads();

    for (int kc = 0; kc < KS; ++kc) {
        int cur = kc & 1;
        if (kc + 1 < KS) {                      // prefetch overlaps this step's MFMA
            stageA(cur ^ 1, kc + 1);
            stageB(cur ^ 1, kc + 1);
        }
        bf16x8 af[4], bfr[4];
#pragma unroll
        for (int i = 0; i < 4; ++i)
            af[i] = *reinterpret_cast<const bf16x8*>(Asm[cur] + (wr * 64 + i * 16 + lr) * 32 + lg * 8);
#pragma unroll
        for (int j = 0; j < 4; ++j)
            bfr[j] = *reinterpret_cast<const bf16x8*>(Bsm[cur] + (wc * 64 + j * 16 + lr) * 32 + lg * 8);
        __builtin_amdgcn_s_setprio(1);
#pragma unroll
        for (int i = 0; i < 4; ++i)
#pragma unroll
            for (int j = 0; j < 4; ++j)
                acc[i][j] = MFMA16(af[i], bfr[j], acc[i][j]);
        __builtin_amdgcn_s_setprio(0);
        __syncthreads();    // drains prefetch (hidden under MFMA) + guards cur-buf reuse
    }

    const int lr4 = lg * 4;
    if constexpr (MODE == 0 || MODE >= 5) {
#pragma unroll
        for (int i = 0; i < 4; ++i)
#pragma unroll
            for (int j = 0; j < 4; ++j) {
                int ocol = nbase + wc * 64 + j * 16 + lr;
#pragma unroll
                for (int r = 0; r < 4; ++r) {
                    int prow = mbase + wr * 64 + i * 16 + lr4 + r;
                    Dbf[(size_t)prow * NC + ocol] = f2bf(acc[i][j][r]);
                }
            }
    } else if constexpr (MODE == 3) {
#pragma unroll
        for (int j = 0; j < 4; ++j) {
            int o = nbase + wc * 64 + j * 16 + lr;
            float sc = g[o] * rsqrtf(va[o] + 1e-5f);
            float sh = be[o] - mu[o] * sc;
#pragma unroll
            for (int i = 0; i < 4; ++i)
#pragma unroll
                for (int r = 0; r < 4; ++r) {
                    int prow = mbase + wr * 64 + i * 16 + lr4 + r;
                    float y = acc[i][j][r] * sc + sh;
                    y = (y >= 0.f) ? y : 0.2f * y;
                    Dbf[(size_t)prow * NOUT + o] = f2bf(y);
                }
        }
    } else {  // MODE 4
#pragma unroll
        for (int j = 0; j < 4; ++j) {
            int pix = nbase + wc * 64 + j * 16 + lr;
            int b = pix / PH, ph = pix % PH;
#pragma unroll
            for (int i = 0; i < 4; ++i)
#pragma unroll
                for (int r = 0; r < 4; ++r) {
                    int o = mbase + wr * 64 + i * 16 + lr4 + r;
                    Df32[((size_t)b * NOUT + o) * PH + ph] = acc[i][j][r];
                }
        }
    }
}

// ---------------- attention: per (b,h), 64 q-rows per block (round-9 structure) ----------------
// QK^T: 20 K-tiles of 16 rows, LDS double-buffered, 2-DEEP register prefetch
// (kregA/kregB), ONE barrier per tile (buf^1 writers only race t-1 readers, who
// passed the previous barrier). PV: 10 V-tiles [512c][32x] slot-swizzled, single
// 32KB buffer, 1-deep prefetch, 2 barriers (proven round-9 form).
__global__ __launch_bounds__(256, 2) void k_attn(
        const unsigned short* __restrict__ Q, const unsigned short* __restrict__ K,
        const unsigned short* __restrict__ Vb, unsigned short* __restrict__ O) {
    __shared__ unsigned short P[64][328];
    __shared__ unsigned short KV[32 * 512];

    int pphys = blockIdx.x;
    int l = (pphys & 7) * 120 + (pphys >> 3);
    int head = l / 5, qt = l % 5;
    int b = head / NH, hh = head % NH;
    int lane = threadIdx.x & 63, w = threadIdx.x >> 6;
    int lr = lane & 15, lg = lane >> 4;
    int rowbase = b * PH + hh * NW;     // pixel index of (b,h, x=0)
    int qrow = rowbase + qt * 64 + w * 16 + lr;

    bf16x8 qf[16];
#pragma unroll
    for (int kc = 0; kc < 16; ++kc)
        qf[kc] = *reinterpret_cast<const bf16x8*>(Q + (size_t)qrow * NC + kc * 32 + lg * 8);

    f32x4 acc[20];
#pragma unroll
    for (int xt = 0; xt < 20; ++xt) acc[xt] = f32x4{0.f, 0.f, 0.f, 0.f};

    // ---- QK^T ----
    // tile t rows: rowbase + t*16 + r; wave w stages rows w*4+j.
    // row r, LDS slot p holds global 16B-slot p^(r&7)  [read swizzle rsw = lr&7]
    u16x8 kregA[4], kregB[4];
    auto kloadTo = [&](int t, u16x8* kr) {
#pragma unroll
        for (int j = 0; j < 4; ++j) {
            int r = w * 4 + j;
            kr[j] = *reinterpret_cast<const u16x8*>(
                K + (size_t)(rowbase + t * 16 + r) * NC + ((lane ^ (r & 7)) * 8));
        }
    };
    auto kwriteFrom = [&](int buf, u16x8* kr) {
#pragma unroll
        for (int j = 0; j < 4; ++j) {
            int r = w * 4 + j;
            *reinterpret_cast<u16x8*>(KV + (buf * 16 + r) * 512 + lane * 8) = kr[j];
        }
    };

    kloadTo(0, kregA);
    kwriteFrom(0, kregA);               // tile 0 -> buf 0 (waits its own vmcnt)
    kloadTo(1, kregB);                  // tile 1 in flight
    __syncthreads();
#pragma unroll
    for (int t = 0; t < 20; ++t) {
        int buf = t & 1;
        if (t + 2 < 20) kloadTo(t + 2, (t & 1) ? kregB : kregA);   // 2-deep prefetch
        int rsw = lr & 7;
        __builtin_amdgcn_s_setprio(1);
#pragma unroll
        for (int kc = 0; kc < 16; ++kc) {
            bf16x8 kf = *reinterpret_cast<const bf16x8*>(
                KV + (buf * 16 + lr) * 512 + (((kc * 4 + lg) ^ rsw) * 8));
            acc[t] = MFMA16(qf[kc], kf, acc[t]);
        }
        __builtin_amdgcn_s_setprio(0);
        // write tile t+1 into buf^1: its last readers were tile t-1, already past
        // the previous barrier -> no race; single barrier per tile.
        if (t + 1 < 20) kwriteFrom(buf ^ 1, (t & 1) ? kregA : kregB);
        __syncthreads();
    }

    // ---- prefetch V tile 0 (hidden under softmax) ----
    u16x8 vreg[8];
    auto vload = [&](int s) {
#pragma unroll
        for (int j = 0; j < 8; ++j) {
            int c = (w * 8 + j) * 16 + (lane >> 2);
            int qg = (lane & 3) ^ ((lane >> 3) & 3);   // global x-quad for this LDS slot
            vreg[j] = *reinterpret_cast<const u16x8*>(
                Vb + (size_t)(b * NC + c) * PH + hh * NW + s * 32 + qg * 8);
        }
    };
    auto vwrite = [&]() {
#pragma unroll
        for (int j = 0; j < 8; ++j)
            *reinterpret_cast<u16x8*>(KV + (w * 8 + j) * 512 + lane * 8) = vreg[j];
    };
    vload(0);

    // ---- softmax (rows lg*4+r live on the 16 lanes sharing lg) ----
#pragma unroll
    for (int xt = 0; xt < 20; ++xt)
#pragma unroll
        for (int r = 0; r < 4; ++r) acc[xt][r] *= 0.125f;
    float m[4] = {-1e30f, -1e30f, -1e30f, -1e30f};
#pragma unroll
    for (int xt = 0; xt < 20; ++xt)
#pragma unroll
        for (int r = 0; r < 4; ++r) m[r] = fmaxf(m[r], acc[xt][r]);
#pragma unroll
    for (int mask = 1; mask < 16; mask <<= 1)
#pragma unroll
        for (int r = 0; r < 4; ++r) m[r] = fmaxf(m[r], __shfl_xor(m[r], mask));
    float s4[4] = {0.f, 0.f, 0.f, 0.f};
#pragma unroll
    for (int xt = 0; xt < 20; ++xt)
#pragma unroll
        for (int r = 0; r < 4; ++r) {
            float e = __expf(acc[xt][r] - m[r]);
            acc[xt][r] = e;
            s4[r] += e;
        }
#pragma unroll
    for (int mask = 1; mask < 16; mask <<= 1)
#pragma unroll
        for (int r = 0; r < 4; ++r) s4[r] += __shfl_xor(s4[r], mask);
    // P -> LDS (unnormalized)
#pragma unroll
    for (int xt = 0; xt < 20; ++xt)
#pragma unroll
        for (int r = 0; r < 4; ++r)
            P[w * 16 + lg * 4 + r][xt * 16 + lr] = f2bf(acc[xt][r]);
    __syncthreads();            // P visible; drains vload(0) (hidden under softmax)
    vwrite();
    __syncthreads();            // V tile 0 visible

    // ---- PV ----
    f32x4 oacc[32];
#pragma unroll
    for (int ct = 0; ct < 32; ++ct) oacc[ct] = f32x4{0.f, 0.f, 0.f, 0.f};

#pragma unroll
    for (int s = 0; s < 10; ++s) {
        if (s + 1 < 10) vload(s + 1);          // overlaps the 32-MFMA cluster
        bf16x8 pf = *reinterpret_cast<const bf16x8*>(&P[w * 16 + lr][s * 32 + lg * 8]);
        __builtin_amdgcn_s_setprio(1);
#pragma unroll
        for (int ct = 0; ct < 32; ++ct) {
            bf16x8 vf = *reinterpret_cast<const bf16x8*>(
                KV + ct * 512 + lr * 32 + ((lg ^ ((lr >> 1) & 3)) * 8));
            oacc[ct] = MFMA16(pf, vf, oacc[ct]);
        }
        __builtin_amdgcn_s_setprio(0);
        __syncthreads();                        // tile-s reads done (+ drains vload)
        if (s + 1 < 10) vwrite();
        __syncthreads();                        // next tile visible
    }

#pragma unroll
    for (int ct = 0; ct < 32; ++ct)
#pragma unroll
        for (int r = 0; r < 4; ++r) {
            int prow = rowbase + qt * 64 + w * 16 + lg * 4 + r;
            O[(size_t)prow * NC + ct * 16 + lr] = f2bf(oacc[ct][r] / s4[r]);
        }
}

extern "C" void kernel_launch(void* const* d_in, const int* in_sizes, int n_in,
                              void* d_out, int out_size, void* d_ws, size_t ws_size,
                              hipStream_t stream) {
    const float* left  = (const float*)d_in[0];
    const float* right = (const float*)d_in[1];
    const float* wq = (const float*)d_in[2];
    const float* wk = (const float*)d_in[3];
    const float* wv = (const float*)d_in[4];
    const float* w1 = (const float*)d_in[5];
    const float* bn_g = (const float*)d_in[6];
    const float* bn_b = (const float*)d_in[7];
    const float* bn_m = (const float*)d_in[8];
    const float* bn_v = (const float*)d_in[9];
    const float* w2 = (const float*)d_in[10];
    float* out = (float*)d_out;

    size_t off = 0;
    auto alloc = [&](size_t bytes) -> void* {
        void* p = (char*)d_ws + off;
        off += (bytes + 255) & ~(size_t)255;
        return p;
    };
    const size_t clb = (size_t)NPIX * NC * 2;        // 62.9 MB
    unsigned short* Lcl = (unsigned short*)alloc(clb);
    unsigned short* Rcl = (unsigned short*)alloc(clb);
    unsigned short* Rbf = (unsigned short*)alloc(clb);
    unsigned short* Qb  = (unsigned short*)alloc(clb);   // T, then aliased by Yb
    unsigned short* Ub  = (unsigned short*)alloc(clb);   // attn @ Rbf
    unsigned short* WqT = (unsigned short*)alloc((size_t)NC * NC * 2);
    unsigned short* WkT = (unsigned short*)alloc((size_t)NC * NC * 2);
    unsigned short* WvT = (unsigned short*)alloc((size_t)NC * NC * 2);
    unsigned short* Mt  = (unsigned short*)alloc((size_t)NC * NC * 2);
    unsigned short* WX  = (unsigned short*)alloc((size_t)NOUT * NC * 2);
    unsigned short* W1b = (unsigned short*)alloc((size_t)NOUT * 1024 * 2);
    unsigned short* W2b = (unsigned short*)alloc((size_t)NOUT * NOUT * 2);
    unsigned short* Yb = Qb;    // y aliases Qb (T dead after attention)

    k_cast<<<dim3((NOUT * 1024 + 255) / 256), 256, 0, stream>>>(w1, W1b, NOUT * 1024);
    k_cast<<<dim3((NOUT * NOUT + 255) / 256), 256, 0, stream>>>(w2, W2b, NOUT * NOUT);

    // WqT/WkT/WvT [c][i] bf16
    k_wtrans<<<dim3(8, 8, 3), 256, 0, stream>>>(wq, wk, wv, WqT, WkT, WvT);

    // Lcl/Rcl channels-last + Rbf straight bf16 copy of right (64px x 128c tiles)
    k_transpose<<<dim3(PH / 64, NC / 128, 4), 256, 0, stream>>>(left, right, Lcl, Rcl, Rbf);

    // Mt[c2][c1] = sum_i wk[i,c2] wq[i,c1]   (B-operand for T-GEMM)
    k_gemm<5><<<dim3(16), 256, 0, stream>>>(WkT, nullptr, WqT, nullptr, Mt, nullptr, nullptr, nullptr, nullptr, nullptr);
    // WX[o2][c] = sum_o w1[o2,512+o] wv[o,c]
    k_gemm<6><<<dim3(8), 256, 0, stream>>>(W1b, nullptr, WvT, nullptr, WX, nullptr, nullptr, nullptr, nullptr, nullptr);

    // T = Lcl @ Mt^T  [61440, 512]
    k_gemm<0><<<dim3(1920), 256, 0, stream>>>(Lcl, nullptr, Mt, nullptr, Qb, nullptr, nullptr, nullptr, nullptr, nullptr);

    // attn: dots = T @ Rcl^T; U = softmax(dots) @ Rbf
    k_attn<<<dim3(960), 256, 0, stream>>>(Qb, Rcl, Rbf, Ub);

    // y = concat(Lcl, U) @ concat(w1L, WX)^T + BN + LeakyReLU
    k_gemm<3><<<dim3(960), 256, 0, stream>>>(Lcl, Ub, W1b, WX, Yb, nullptr, bn_g, bn_b, bn_m, bn_v);

    // out^T = W2 @ Y^T, f32 channels-first
    k_gemm<4><<<dim3(960), 256, 0, stream>>>(W2b, nullptr, Yb, nullptr, nullptr, out, nullptr, nullptr, nullptr, nullptr);
}

// Round 16
// 349.754 us; speedup vs baseline: 2.1565x; 1.0008x over previous
//
#include <hip/hip_runtime.h>

typedef __bf16 bf16x8 __attribute__((ext_vector_type(8)));
typedef float f32x4 __attribute__((ext_vector_type(4)));
typedef unsigned short u16x8 __attribute__((ext_vector_type(8)));
typedef unsigned short u16x4 __attribute__((ext_vector_type(4)));

#define MFMA16(a, b, c) __builtin_amdgcn_mfma_f32_16x16x32_bf16((a), (b), (c), 0, 0, 0)
#define GLOAD_LDS(gp, lp) __builtin_amdgcn_global_load_lds( \
    (const __attribute__((address_space(1))) void*)(uintptr_t)(const void*)(gp), \
    (__attribute__((address_space(3))) void*)(uintptr_t)(void*)(lp), 16, 0, 0)

// dims
#define NB 2
#define NC 512
#define NH 96
#define NW 320
#define PH 30720      // NH*NW pixels per batch
#define NPIX 61440    // NB*PH
#define NOUT 256

__device__ __forceinline__ unsigned short f2bf(float f) {
    union { float f; unsigned u; } v; v.f = f;
    unsigned r = v.u + 0x7fffu + ((v.u >> 16) & 1u);
    return (unsigned short)(r >> 16);
}

// ---------------- weight cast f32 -> bf16 ----------------
__global__ void k_cast(const float* __restrict__ src, unsigned short* __restrict__ dst, int n) {
    int i = blockIdx.x * 256 + threadIdx.x;
    if (i < n) dst[i] = f2bf(src[i]);
}

// ---------------- small weight transpose [512,512] f32 -> [512,512] bf16 (transposed) ----------------
__global__ __launch_bounds__(256) void k_wtrans(
        const float* __restrict__ wq, const float* __restrict__ wk, const float* __restrict__ wv,
        unsigned short* __restrict__ WqT, unsigned short* __restrict__ WkT, unsigned short* __restrict__ WvT) {
    __shared__ float t[64][65];
    int z = blockIdx.z;
    const float* src = (z == 0) ? wq : (z == 1) ? wk : wv;
    unsigned short* dst = (z == 0) ? WqT : (z == 1) ? WkT : WvT;
    int i0 = blockIdx.y * 64;   // input row (i)
    int c0 = blockIdx.x * 64;   // input col (c)
    int tt = threadIdx.x;
    int r4 = tt >> 4, px = (tt & 15) * 4;
#pragma unroll
    for (int i = 0; i < 4; ++i) {
        int il = i * 16 + r4;
        f32x4 v = *reinterpret_cast<const f32x4*>(src + (size_t)(i0 + il) * 512 + c0 + px);
        t[il][px + 0] = v[0]; t[il][px + 1] = v[1]; t[il][px + 2] = v[2]; t[il][px + 3] = v[3];
    }
    __syncthreads();
    int cc = (tt & 7) * 8, pl0 = tt >> 3;
#pragma unroll
    for (int j = 0; j < 2; ++j) {
        int pl = j * 32 + pl0;
        u16x8 ov;
#pragma unroll
        for (int i = 0; i < 8; ++i) ov[i] = f2bf(t[cc + i][pl]);
        *reinterpret_cast<u16x8*>(dst + (size_t)(c0 + pl) * 512 + i0 + cc) = ov;   // dst[c][i]
    }
}

// ---------------- transpose [b,c,hw] f32 -> [b,hw,c] bf16; right also -> straight bf16 copy ----------------
// tile 64 px x 128 c. Column swizzle col ^= 4*((row>>5)&3) on BOTH phases breaks the
// 4-way phase-2 bank conflict (8p mod 32 degeneracy) down to 2-way (= free, m136).
__global__ __launch_bounds__(256) void k_transpose(
        const float* __restrict__ L, const float* __restrict__ R,
        unsigned short* __restrict__ Lcl, unsigned short* __restrict__ Rcl,
        unsigned short* __restrict__ Rbf) {
    __shared__ float t[128][65];
    int z = blockIdx.z;                 // which*2 + b
    int b = z & 1, which = z >> 1;
    const float* src = which ? R : L;
    unsigned short* dst = which ? Rcl : Lcl;
    int c0 = blockIdx.y * 128;
    int p0 = blockIdx.x * 64;
    int tt = threadIdx.x;

    int cl16 = tt >> 4;                 // 0..15
    int px = (tt & 15) * 4;
#pragma unroll
    for (int i = 0; i < 8; ++i) {
        int cl = i * 16 + cl16;
        f32x4 v = *reinterpret_cast<const f32x4*>(src + (size_t)(b * NC + c0 + cl) * PH + p0 + px);
        int pc = px ^ (((cl >> 5) & 3) << 2);   // swizzled column base (bits 2-3)
        t[cl][pc + 0] = v[0];
        t[cl][pc + 1] = v[1];
        t[cl][pc + 2] = v[2];
        t[cl][pc + 3] = v[3];
        if (which) {                    // straight bf16 copy of right (original layout)
            u16x4 sv;
#pragma unroll
            for (int k = 0; k < 4; ++k) sv[k] = f2bf(v[k]);
            *reinterpret_cast<u16x4*>(Rbf + (size_t)(b * NC + c0 + cl) * PH + p0 + px) = sv;
        }
    }
    __syncthreads();

    int cc = (tt & 15) * 8;             // 0..120
    int pl16 = tt >> 4;                 // 0..15
#pragma unroll
    for (int j = 0; j < 4; ++j) {
        int pl = j * 16 + pl16;
        u16x8 ov;
#pragma unroll
        for (int i = 0; i < 8; ++i) {
            int row = cc + i;
            ov[i] = f2bf(t[row][pl ^ (((row >> 5) & 3) << 2)]);
        }
        *reinterpret_cast<u16x8*>(dst + (size_t)(b * PH + p0 + pl) * NC + c0 + cc) = ov;
    }
}

// ================= staged 128x128-tile GEMM, double-buffered prefetch =================
// MODE 0: T   = Lcl @ Mt^T        D[pix, c2]  bf16   (replaces Q projection)
// MODE 3: y   = concat(Lcl,U) @ concat(w1L,WX)^T, BN+LeakyReLU   D[pix, o] bf16
// MODE 4: out^T = W2 @ Y^T        D[o, pix] -> f32 channels-first (coalesced)
// MODE 5: Mt  = WkT @ WqT^T       D[c2, c1]   bf16 (512x512, 16 blocks)
// MODE 6: WX  = w1O @ WvT^T       D[o2, c]    bf16 (256x512, 8 blocks)
template <int MODE>
__global__ __launch_bounds__(256) void k_gemm(
        const unsigned short* __restrict__ A0,
        const unsigned short* __restrict__ A1,
        const unsigned short* __restrict__ Bb,
        const unsigned short* __restrict__ Bb2,
        unsigned short* __restrict__ Dbf,
        float* __restrict__ Df32,
        const float* __restrict__ g, const float* __restrict__ be,
        const float* __restrict__ mu, const float* __restrict__ va) {
    constexpr int SA = (MODE == 4) ? NOUT : (MODE == 6) ? 1024 : NC;  // A row stride
    constexpr int AOFF = (MODE == 6) ? 512 : 0;                       // A col offset (w1O slice)
    constexpr int SB = (MODE == 3) ? 1024 : (MODE == 4) ? NOUT : NC;
    constexpr int KS = (MODE == 3) ? 32 : (MODE == 4) ? 8 : 16;       // K-steps of 32
    constexpr int NTO = (MODE == 3 || MODE == 4) ? 2 : 4;             // n-tile count
    constexpr int TOT = (MODE == 5) ? 16 : (MODE == 6) ? 8 : ((MODE == 3 || MODE == 4) ? 960 : 1920);

    __shared__ unsigned short Asm[2][128 * 32];
    __shared__ unsigned short Bsm[2][128 * 32];

    int pphys = blockIdx.x;
    int lgc = (pphys & 7) * (TOT / 8) + (pphys >> 3);
    int pixt = lgc / NTO, ot = lgc % NTO;
    const int mbase = ((MODE == 4) ? ot : pixt) * 128;
    const int nbase = ((MODE == 4) ? pixt : ot) * 128;

    const int lane = threadIdx.x & 63, w = threadIdx.x >> 6;
    const int lr = lane & 15, lg = lane >> 4;
    const int wr = w >> 1, wc = w & 1;

    // stage one 128x32 bf16 tile: 512 chunks of 16B; wave w owns chunks [w*128, w*128+128)
    auto stageA = [&](int buf, int kc) {
        const unsigned short* srcA = A0;
        int colOff = kc * 32;
        if constexpr (MODE == 3) {
            if (kc >= 16) { srcA = A1; colOff = (kc - 16) * 32; }
        }
#pragma unroll
        for (int j = 0; j < 2; ++j) {
            int cb = w * 128 + j * 64;           // wave-uniform chunk base
            int c = cb + lane;
            const unsigned short* gp = srcA + (size_t)(mbase + (c >> 2)) * SA + AOFF + colOff + (c & 3) * 8;
            GLOAD_LDS(gp, Asm[buf] + cb * 8);
        }
    };
    auto stageB = [&](int buf, int kc) {
        const unsigned short* srcB = Bb;
        int colOff = kc * 32;
        int sb = SB;
        if constexpr (MODE == 3) {
            if (kc >= 16) { srcB = Bb2; colOff = (kc - 16) * 32; sb = 512; }
        }
#pragma unroll
        for (int j = 0; j < 2; ++j) {
            int cb = w * 128 + j * 64;
            int c = cb + lane;
            const unsigned short* gp = srcB + (size_t)(nbase + (c >> 2)) * sb + colOff + (c & 3) * 8;
            GLOAD_LDS(gp, Bsm[buf] + cb * 8);
        }
    };

    f32x4 acc[4][4] = {};

    stageA(0, 0);
    stageB(0, 0);
    __syncthreads();

    for (int kc = 0; kc < KS; ++kc) {
        int cur = kc & 1;
        if (kc + 1 < KS) {                      // prefetch overlaps this step's MFMA
            stageA(cur ^ 1, kc + 1);
            stageB(cur ^ 1, kc + 1);
        }
        bf16x8 af[4], bfr[4];
#pragma unroll
        for (int i = 0; i < 4; ++i)
            af[i] = *reinterpret_cast<const bf16x8*>(Asm[cur] + (wr * 64 + i * 16 + lr) * 32 + lg * 8);
#pragma unroll
        for (int j = 0; j < 4; ++j)
            bfr[j] = *reinterpret_cast<const bf16x8*>(Bsm[cur] + (wc * 64 + j * 16 + lr) * 32 + lg * 8);
        __builtin_amdgcn_s_setprio(1);
#pragma unroll
        for (int i = 0; i < 4; ++i)
#pragma unroll
            for (int j = 0; j < 4; ++j)
                acc[i][j] = MFMA16(af[i], bfr[j], acc[i][j]);
        __builtin_amdgcn_s_setprio(0);
        __syncthreads();    // drains prefetch (hidden under MFMA) + guards cur-buf reuse
    }

    const int lr4 = lg * 4;
    if constexpr (MODE == 0 || MODE >= 5) {
#pragma unroll
        for (int i = 0; i < 4; ++i)
#pragma unroll
            for (int j = 0; j < 4; ++j) {
                int ocol = nbase + wc * 64 + j * 16 + lr;
#pragma unroll
                for (int r = 0; r < 4; ++r) {
                    int prow = mbase + wr * 64 + i * 16 + lr4 + r;
                    Dbf[(size_t)prow * NC + ocol] = f2bf(acc[i][j][r]);
                }
            }
    } else if constexpr (MODE == 3) {
#pragma unroll
        for (int j = 0; j < 4; ++j) {
            int o = nbase + wc * 64 + j * 16 + lr;
            float sc = g[o] * rsqrtf(va[o] + 1e-5f);
            float sh = be[o] - mu[o] * sc;
#pragma unroll
            for (int i = 0; i < 4; ++i)
#pragma unroll
                for (int r = 0; r < 4; ++r) {
                    int prow = mbase + wr * 64 + i * 16 + lr4 + r;
                    float y = acc[i][j][r] * sc + sh;
                    y = (y >= 0.f) ? y : 0.2f * y;
                    Dbf[(size_t)prow * NOUT + o] = f2bf(y);
                }
        }
    } else {  // MODE 4
#pragma unroll
        for (int j = 0; j < 4; ++j) {
            int pix = nbase + wc * 64 + j * 16 + lr;
            int b = pix / PH, ph = pix % PH;
#pragma unroll
            for (int i = 0; i < 4; ++i)
#pragma unroll
                for (int r = 0; r < 4; ++r) {
                    int o = mbase + wr * 64 + i * 16 + lr4 + r;
                    Df32[((size_t)b * NOUT + o) * PH + ph] = acc[i][j][r];
                }
        }
    }
}

// ---------------- attention: per (b,h), 64 q-rows per block (round-15 structure) ----------------
// QK^T: 20 K-tiles of 16 rows, LDS double-buffered, 2-DEEP register prefetch
// (kregA/kregB), ONE barrier per tile (buf^1 writers only race t-1 readers, who
// passed the previous barrier). PV: 10 V-tiles [512c][32x] slot-swizzled, single
// 32KB buffer, 1-deep prefetch, 2 barriers (proven round-9 form).
__global__ __launch_bounds__(256, 2) void k_attn(
        const unsigned short* __restrict__ Q, const unsigned short* __restrict__ K,
        const unsigned short* __restrict__ Vb, unsigned short* __restrict__ O) {
    __shared__ unsigned short P[64][328];
    __shared__ unsigned short KV[32 * 512];

    int pphys = blockIdx.x;
    int l = (pphys & 7) * 120 + (pphys >> 3);
    int head = l / 5, qt = l % 5;
    int b = head / NH, hh = head % NH;
    int lane = threadIdx.x & 63, w = threadIdx.x >> 6;
    int lr = lane & 15, lg = lane >> 4;
    int rowbase = b * PH + hh * NW;     // pixel index of (b,h, x=0)
    int qrow = rowbase + qt * 64 + w * 16 + lr;

    bf16x8 qf[16];
#pragma unroll
    for (int kc = 0; kc < 16; ++kc)
        qf[kc] = *reinterpret_cast<const bf16x8*>(Q + (size_t)qrow * NC + kc * 32 + lg * 8);

    f32x4 acc[20];
#pragma unroll
    for (int xt = 0; xt < 20; ++xt) acc[xt] = f32x4{0.f, 0.f, 0.f, 0.f};

    // ---- QK^T ----
    // tile t rows: rowbase + t*16 + r; wave w stages rows w*4+j.
    // row r, LDS slot p holds global 16B-slot p^(r&7)  [read swizzle rsw = lr&7]
    u16x8 kregA[4], kregB[4];
    auto kloadTo = [&](int t, u16x8* kr) {
#pragma unroll
        for (int j = 0; j < 4; ++j) {
            int r = w * 4 + j;
            kr[j] = *reinterpret_cast<const u16x8*>(
                K + (size_t)(rowbase + t * 16 + r) * NC + ((lane ^ (r & 7)) * 8));
        }
    };
    auto kwriteFrom = [&](int buf, u16x8* kr) {
#pragma unroll
        for (int j = 0; j < 4; ++j) {
            int r = w * 4 + j;
            *reinterpret_cast<u16x8*>(KV + (buf * 16 + r) * 512 + lane * 8) = kr[j];
        }
    };

    kloadTo(0, kregA);
    kwriteFrom(0, kregA);               // tile 0 -> buf 0 (waits its own vmcnt)
    kloadTo(1, kregB);                  // tile 1 in flight
    __syncthreads();
#pragma unroll
    for (int t = 0; t < 20; ++t) {
        int buf = t & 1;
        if (t + 2 < 20) kloadTo(t + 2, (t & 1) ? kregB : kregA);   // 2-deep prefetch
        int rsw = lr & 7;
        __builtin_amdgcn_s_setprio(1);
#pragma unroll
        for (int kc = 0; kc < 16; ++kc) {
            bf16x8 kf = *reinterpret_cast<const bf16x8*>(
                KV + (buf * 16 + lr) * 512 + (((kc * 4 + lg) ^ rsw) * 8));
            acc[t] = MFMA16(qf[kc], kf, acc[t]);
        }
        __builtin_amdgcn_s_setprio(0);
        // write tile t+1 into buf^1: its last readers were tile t-1, already past
        // the previous barrier -> no race; single barrier per tile.
        if (t + 1 < 20) kwriteFrom(buf ^ 1, (t & 1) ? kregA : kregB);
        __syncthreads();
    }

    // ---- prefetch V tile 0 (hidden under softmax) ----
    u16x8 vreg[8];
    auto vload = [&](int s) {
#pragma unroll
        for (int j = 0; j < 8; ++j) {
            int c = (w * 8 + j) * 16 + (lane >> 2);
            int qg = (lane & 3) ^ ((lane >> 3) & 3);   // global x-quad for this LDS slot
            vreg[j] = *reinterpret_cast<const u16x8*>(
                Vb + (size_t)(b * NC + c) * PH + hh * NW + s * 32 + qg * 8);
        }
    };
    auto vwrite = [&]() {
#pragma unroll
        for (int j = 0; j < 8; ++j)
            *reinterpret_cast<u16x8*>(KV + (w * 8 + j) * 512 + lane * 8) = vreg[j];
    };
    vload(0);

    // ---- softmax (rows lg*4+r live on the 16 lanes sharing lg) ----
#pragma unroll
    for (int xt = 0; xt < 20; ++xt)
#pragma unroll
        for (int r = 0; r < 4; ++r) acc[xt][r] *= 0.125f;
    float m[4] = {-1e30f, -1e30f, -1e30f, -1e30f};
#pragma unroll
    for (int xt = 0; xt < 20; ++xt)
#pragma unroll
        for (int r = 0; r < 4; ++r) m[r] = fmaxf(m[r], acc[xt][r]);
#pragma unroll
    for (int mask = 1; mask < 16; mask <<= 1)
#pragma unroll
        for (int r = 0; r < 4; ++r) m[r] = fmaxf(m[r], __shfl_xor(m[r], mask));
    float s4[4] = {0.f, 0.f, 0.f, 0.f};
#pragma unroll
    for (int xt = 0; xt < 20; ++xt)
#pragma unroll
        for (int r = 0; r < 4; ++r) {
            float e = __expf(acc[xt][r] - m[r]);
            acc[xt][r] = e;
            s4[r] += e;
        }
#pragma unroll
    for (int mask = 1; mask < 16; mask <<= 1)
#pragma unroll
        for (int r = 0; r < 4; ++r) s4[r] += __shfl_xor(s4[r], mask);
    // P -> LDS (unnormalized)
#pragma unroll
    for (int xt = 0; xt < 20; ++xt)
#pragma unroll
        for (int r = 0; r < 4; ++r)
            P[w * 16 + lg * 4 + r][xt * 16 + lr] = f2bf(acc[xt][r]);
    __syncthreads();            // P visible; drains vload(0) (hidden under softmax)
    vwrite();
    __syncthreads();            // V tile 0 visible

    // ---- PV ----
    f32x4 oacc[32];
#pragma unroll
    for (int ct = 0; ct < 32; ++ct) oacc[ct] = f32x4{0.f, 0.f, 0.f, 0.f};

#pragma unroll
    for (int s = 0; s < 10; ++s) {
        if (s + 1 < 10) vload(s + 1);          // overlaps the 32-MFMA cluster
        bf16x8 pf = *reinterpret_cast<const bf16x8*>(&P[w * 16 + lr][s * 32 + lg * 8]);
        __builtin_amdgcn_s_setprio(1);
#pragma unroll
        for (int ct = 0; ct < 32; ++ct) {
            bf16x8 vf = *reinterpret_cast<const bf16x8*>(
                KV + ct * 512 + lr * 32 + ((lg ^ ((lr >> 1) & 3)) * 8));
            oacc[ct] = MFMA16(pf, vf, oacc[ct]);
        }
        __builtin_amdgcn_s_setprio(0);
        __syncthreads();                        // tile-s reads done (+ drains vload)
        if (s + 1 < 10) vwrite();
        __syncthreads();                        // next tile visible
    }

#pragma unroll
    for (int ct = 0; ct < 32; ++ct)
#pragma unroll
        for (int r = 0; r < 4; ++r) {
            int prow = rowbase + qt * 64 + w * 16 + lg * 4 + r;
            O[(size_t)prow * NC + ct * 16 + lr] = f2bf(oacc[ct][r] / s4[r]);
        }
}

extern "C" void kernel_launch(void* const* d_in, const int* in_sizes, int n_in,
                              void* d_out, int out_size, void* d_ws, size_t ws_size,
                              hipStream_t stream) {
    const float* left  = (const float*)d_in[0];
    const float* right = (const float*)d_in[1];
    const float* wq = (const float*)d_in[2];
    const float* wk = (const float*)d_in[3];
    const float* wv = (const float*)d_in[4];
    const float* w1 = (const float*)d_in[5];
    const float* bn_g = (const float*)d_in[6];
    const float* bn_b = (const float*)d_in[7];
    const float* bn_m = (const float*)d_in[8];
    const float* bn_v = (const float*)d_in[9];
    const float* w2 = (const float*)d_in[10];
    float* out = (float*)d_out;

    size_t off = 0;
    auto alloc = [&](size_t bytes) -> void* {
        void* p = (char*)d_ws + off;
        off += (bytes + 255) & ~(size_t)255;
        return p;
    };
    const size_t clb = (size_t)NPIX * NC * 2;        // 62.9 MB
    unsigned short* Lcl = (unsigned short*)alloc(clb);
    unsigned short* Rcl = (unsigned short*)alloc(clb);
    unsigned short* Rbf = (unsigned short*)alloc(clb);
    unsigned short* Qb  = (unsigned short*)alloc(clb);   // T, then aliased by Yb
    unsigned short* Ub  = (unsigned short*)alloc(clb);   // attn @ Rbf
    unsigned short* WqT = (unsigned short*)alloc((size_t)NC * NC * 2);
    unsigned short* WkT = (unsigned short*)alloc((size_t)NC * NC * 2);
    unsigned short* WvT = (unsigned short*)alloc((size_t)NC * NC * 2);
    unsigned short* Mt  = (unsigned short*)alloc((size_t)NC * NC * 2);
    unsigned short* WX  = (unsigned short*)alloc((size_t)NOUT * NC * 2);
    unsigned short* W1b = (unsigned short*)alloc((size_t)NOUT * 1024 * 2);
    unsigned short* W2b = (unsigned short*)alloc((size_t)NOUT * NOUT * 2);
    unsigned short* Yb = Qb;    // y aliases Qb (T dead after attention)

    k_cast<<<dim3((NOUT * 1024 + 255) / 256), 256, 0, stream>>>(w1, W1b, NOUT * 1024);
    k_cast<<<dim3((NOUT * NOUT + 255) / 256), 256, 0, stream>>>(w2, W2b, NOUT * NOUT);

    // WqT/WkT/WvT [c][i] bf16
    k_wtrans<<<dim3(8, 8, 3), 256, 0, stream>>>(wq, wk, wv, WqT, WkT, WvT);

    // Lcl/Rcl channels-last + Rbf straight bf16 copy of right (64px x 128c tiles)
    k_transpose<<<dim3(PH / 64, NC / 128, 4), 256, 0, stream>>>(left, right, Lcl, Rcl, Rbf);

    // Mt[c2][c1] = sum_i wk[i,c2] wq[i,c1]   (B-operand for T-GEMM)
    k_gemm<5><<<dim3(16), 256, 0, stream>>>(WkT, nullptr, WqT, nullptr, Mt, nullptr, nullptr, nullptr, nullptr, nullptr);
    // WX[o2][c] = sum_o w1[o2,512+o] wv[o,c]
    k_gemm<6><<<dim3(8), 256, 0, stream>>>(W1b, nullptr, WvT, nullptr, WX, nullptr, nullptr, nullptr, nullptr, nullptr);

    // T = Lcl @ Mt^T  [61440, 512]
    k_gemm<0><<<dim3(1920), 256, 0, stream>>>(Lcl, nullptr, Mt, nullptr, Qb, nullptr, nullptr, nullptr, nullptr, nullptr);

    // attn: dots = T @ Rcl^T; U = softmax(dots) @ Rbf
    k_attn<<<dim3(960), 256, 0, stream>>>(Qb, Rcl, Rbf, Ub);

    // y = concat(Lcl, U) @ concat(w1L, WX)^T + BN + LeakyReLU
    k_gemm<3><<<dim3(960), 256, 0, stream>>>(Lcl, Ub, W1b, WX, Yb, nullptr, bn_g, bn_b, bn_m, bn_v);

    // out^T = W2 @ Y^T, f32 channels-first
    k_gemm<4><<<dim3(960), 256, 0, stream>>>(W2b, nullptr, Yb, nullptr, nullptr, out, nullptr, nullptr, nullptr, nullptr);
}